// Round 14
// baseline (144.828 us; speedup 1.0000x reference)
//
#include <hip/hip_runtime.h>
#include <hip/hip_bf16.h>
#include <cstdint>

#define Bn 8
#define Tn 512
#define Dn 1024
#define Hn 16
#define DKn 64
#define Mn (Bn * Tn)   // 4096

typedef unsigned short u16;
typedef short bf16x8 __attribute__((ext_vector_type(8)));
typedef float f32x4 __attribute__((ext_vector_type(4)));

__device__ __forceinline__ u16 f2bf(float f) {
  unsigned int u = __builtin_bit_cast(unsigned int, f);
  u += 0x7fffu + ((u >> 16) & 1u);
  return (u16)(u >> 16);
}
__device__ __forceinline__ float bf2f(u16 v) {
  return __builtin_bit_cast(float, (unsigned int)v << 16);
}
__device__ __forceinline__ unsigned int pack2bf(float lo, float hi) {
  return (unsigned int)f2bf(lo) | ((unsigned int)f2bf(hi) << 16);
}

// async global->LDS, 16B per lane; lds ptr wave-uniform + lane*16.
__device__ __forceinline__ void gl2lds16(const void* g, void* l) {
  __builtin_amdgcn_global_load_lds(
      (const __attribute__((address_space(1))) unsigned int*)g,
      (__attribute__((address_space(3))) unsigned int*)l,
      16, 0, 0);
}

// raw workgroup barrier: compiler memory fence only (no sched pin — m141).
__device__ __forceinline__ void bar() {
  asm volatile("" ::: "memory");
  __builtin_amdgcn_s_barrier();
  asm volatile("" ::: "memory");
}
#define WAITV(n_) asm volatile("s_waitcnt vmcnt(" #n_ ")" ::: "memory")

// ---------------------------------------------------------------------------
// prep: x->bf16, QKV weight transpose, W transposes (one dispatcher kernel).
// ---------------------------------------------------------------------------
__global__ __launch_bounds__(256) void prep_k(
    const float* __restrict__ x, u16* __restrict__ xb,
    const float* __restrict__ wq, const float* __restrict__ wk,
    const float* __restrict__ wv, u16* __restrict__ wqkvT,
    const float* __restrict__ W, const float* __restrict__ W1,
    const float* __restrict__ W2, u16* __restrict__ wt,
    u16* __restrict__ w1t, u16* __restrict__ w2t)
{
  const int bid = blockIdx.x;
  const int t = threadIdx.x;
  if (bid < 2048) {
    const size_t i = ((size_t)bid * 256 + t) * 8;
    float4 a = *reinterpret_cast<const float4*>(&x[i]);
    float4 b = *reinterpret_cast<const float4*>(&x[i + 4]);
    uint4 w;
    w.x = pack2bf(a.x, a.y); w.y = pack2bf(a.z, a.w);
    w.z = pack2bf(b.x, b.y); w.w = pack2bf(b.z, b.w);
    *reinterpret_cast<uint4*>(&xb[i]) = w;
  } else if (bid < 2816) {
    const int idx = bid - 2048;
    const int kt = idx & 15;
    const int y  = idx >> 4;
    const int tau = y >> 4, head = y & 15;
    const float* src = (tau == 0 ? wq : tau == 1 ? wk : wv) + (size_t)head * 65536;
    const int n  = t & 63;
    const int kq = (t >> 6) << 4;
    const int k0 = kt << 6;
    u16 v[16];
#pragma unroll
    for (int j = 0; j < 16; j++)
      v[j] = f2bf(src[(size_t)(k0 + kq + j) * 64 + n]);
    u16* d = &wqkvT[((size_t)tau * 1024 + head * 64 + n) * 1024 + k0 + kq];
    *reinterpret_cast<uint4*>(&d[0]) = *reinterpret_cast<uint4*>(&v[0]);
    *reinterpret_cast<uint4*>(&d[8]) = *reinterpret_cast<uint4*>(&v[8]);
  } else {
    const int idx = bid - 2816;
    const int kt = idx & 15;
    const int rest = idx >> 4;
    const int ntl = rest & 15, z = rest >> 4;
    const float* src = (z == 0 ? W : z == 1 ? W1 : W2);
    u16* dst = (z == 0 ? wt : z == 1 ? w1t : w2t);
    const int n  = (ntl << 6) + (t & 63);
    const int kq = (t >> 6) << 4;
    const int k0 = kt << 6;
    u16 v[16];
#pragma unroll
    for (int j = 0; j < 16; j++)
      v[j] = f2bf(src[(size_t)(k0 + kq + j) * 1024 + n]);
    u16* d = &dst[(size_t)n * 1024 + k0 + kq];
    *reinterpret_cast<uint4*>(&d[0]) = *reinterpret_cast<uint4*>(&v[0]);
    *reinterpret_cast<uint4*>(&d[8]) = *reinterpret_cast<uint4*>(&v[8]);
  }
}

// ---------------------------------------------------------------------------
// Big-grid bf16 MFMA GEMM (QKV): tile 128x128, BK=32, 512 thr = 8 waves 2x4,
// wave-tile 64x32. RING-2 LDS, 1-deep prefetch with counted vmcnt + raw
// barrier pair per K-step (two barriers: stage-ready + read-done; the
// single-barrier variant raced under graph replay — round 13).
// VT: blocks bx>=16 write V transposed via LDS transpose (coalesced 64B runs).
// ---------------------------------------------------------------------------
template<int VT>
__global__ __launch_bounds__(512) void mgemm_k(
    const u16* __restrict__ A, const u16* __restrict__ Bt,
    u16* __restrict__ Cb, int ldc, u16* __restrict__ Vt)
{
  __shared__ __align__(16) u16 As[2][4480];   // buf stride 8960B; tile uses 8192B
  __shared__ __align__(16) u16 Bs[2][4480];

  const int nwg = gridDim.x * gridDim.y;
  const int fid = blockIdx.y * gridDim.x + blockIdx.x;
  const int lid = (fid & 7) * (nwg >> 3) + (fid >> 3);
  const int bx = lid % gridDim.x, by = lid / gridDim.x;

  const int tid  = threadIdx.x;
  const int lane = tid & 63;
  const int wid  = tid >> 6;
  const int wm = wid >> 2, wn = wid & 3;
  const int g4 = lane >> 4, r15 = lane & 15;
  const int m0 = by << 7, n0 = bx << 7;

  const int srow  = tid >> 2;
  const int sslot = tid & 3;
  const int ssw   = (srow ^ (srow >> 2)) & 3;
  const int sk8   = ((sslot ^ ssw) << 3);
  const u16* ga0 = &A[(size_t)(m0 + srow) * 1024 + sk8];
  const u16* gb0 = &Bt[(size_t)(n0 + srow) * 1024 + sk8];
  const int lofs = wid * 1024;

  f32x4 acc[4][2] = {};

  auto stage_t = [&](int t, int buf) {
    gl2lds16(ga0 + t * 32, (char*)As[buf] + lofs);
    gl2lds16(gb0 + t * 32, (char*)Bs[buf] + lofs);
  };
  auto compute_t = [&](int buf) {
    bf16x8 af[4], bfr[2];
#pragma unroll
    for (int m = 0; m < 4; m++) {
      int row = wm * 64 + m * 16 + r15;
      int sw = (row ^ (row >> 2)) & 3;
      af[m] = *reinterpret_cast<const bf16x8*>(
          (const char*)As[buf] + row * 64 + ((g4 ^ sw) << 4));
    }
#pragma unroll
    for (int n = 0; n < 2; n++) {
      int row = wn * 32 + n * 16 + r15;
      int sw = (row ^ (row >> 2)) & 3;
      bfr[n] = *reinterpret_cast<const bf16x8*>(
          (const char*)Bs[buf] + row * 64 + ((g4 ^ sw) << 4));
    }
#pragma unroll
    for (int m = 0; m < 4; m++)
#pragma unroll
      for (int n = 0; n < 2; n++)
        acc[m][n] = __builtin_amdgcn_mfma_f32_16x16x32_bf16(af[m], bfr[n], acc[m][n], 0, 0, 0);
  };

  // ring-2, 1-deep prefetch, two barriers per K-step (verified-safe).
  stage_t(0, 0);
#pragma unroll 1
  for (int t = 0; t < 31; ++t) {
    stage_t(t + 1, (t + 1) & 1);   // 4 in flight
    WAITV(2);                      // tile t landed; t+1 stays in flight
    bar();
    compute_t(t & 1);
    bar();                         // all waves done reading buf t&1
  }
  WAITV(0);
  bar();
  compute_t(1);

  if (VT && bx >= 16) {
    // V^T via LDS transpose: stage C-frags bf16 as [cv][136 u16] rows
    // (cv<64 -> As, else Bs), then write coalesced 64B runs per (dk, s).
    bar();   // all waves done reading compute LDS
    const int vcol0 = n0 - 2048;
#pragma unroll
    for (int m = 0; m < 4; m++) {
      int sloc = wm * 64 + m * 16 + g4 * 4;
#pragma unroll
      for (int n = 0; n < 2; n++) {
        int cv = wn * 32 + n * 16 + r15;
        u16* base = (cv < 64) ? (u16*)As : (u16*)Bs;
        uint2 pk;
        pk.x = pack2bf(acc[m][n][0], acc[m][n][1]);
        pk.y = pack2bf(acc[m][n][2], acc[m][n][3]);
        *reinterpret_cast<uint2*>(&base[(size_t)(cv & 63) * 136 + sloc]) = pk;
      }
    }
    bar();
    {
      int cv = tid >> 2;                 // 0..127
      int sch = (tid & 3) << 5;          // 0,32,64,96
      const u16* base = (cv < 64) ? (const u16*)As : (const u16*)Bs;
      const u16* src = &base[(size_t)(cv & 63) * 136 + sch];
      uint4 v0 = *reinterpret_cast<const uint4*>(src);
      uint4 v1 = *reinterpret_cast<const uint4*>(src + 8);
      uint4 v2 = *reinterpret_cast<const uint4*>(src + 16);
      uint4 v3 = *reinterpret_cast<const uint4*>(src + 24);
      int vcol = vcol0 + cv;
      int hh = vcol >> 6, dk = vcol & 63;
      int bI = m0 >> 9, sbase = (m0 & 511) + sch;
      u16* dst = &Vt[(((size_t)(bI * 16 + hh) * 64 + dk) << 9) + sbase];
      *reinterpret_cast<uint4*>(dst) = v0;
      *reinterpret_cast<uint4*>(dst + 8) = v1;
      *reinterpret_cast<uint4*>(dst + 16) = v2;
      *reinterpret_cast<uint4*>(dst + 24) = v3;
    }
    return;
  }

#pragma unroll
  for (int m = 0; m < 4; m++) {
    int row = m0 + wm * 64 + m * 16 + g4 * 4;
#pragma unroll
    for (int n = 0; n < 2; n++) {
      int col = n0 + wn * 32 + n * 16 + r15;
#pragma unroll
      for (int j = 0; j < 4; j++)
        Cb[(size_t)(row + j) * ldc + col] = f2bf(acc[m][n][j]);
    }
  }
}

// ---------------------------------------------------------------------------
// Small-N bf16 MFMA GEMM (proj/FFN, N=1024): tile 64x128, grid (8,64)=512
// blocks, 512 thr = 8 waves 2x4, wave-tile 32x32. Ring-3 LDS, 2-deep
// prefetch, counted vmcnt, two barriers per K-step (verified-safe).
// OUTM: 1=bf16 C, 2=none. RES: r=acc(+bias)+res(bf16) -> Rout(bf16) + stats.
// RESNORM: res = BN(RresB) on the fly (scale/shift per col).
// ---------------------------------------------------------------------------
template<int BIAS, int RELU, int OUTM, int RES, int RESNORM>
__global__ __launch_bounds__(512) void mgemm64_k(
    const u16* __restrict__ A, const u16* __restrict__ Bt,
    const float* __restrict__ bias, u16* __restrict__ Cb,
    const u16* __restrict__ RresB, u16* __restrict__ Rout,
    float* __restrict__ psum, float* __restrict__ psumsq,
    const float* __restrict__ nsc, const float* __restrict__ nsh)
{
  __shared__ __align__(16) u16 As[3][2048];   // [buf][64 rows][32 k]
  __shared__ __align__(16) u16 Bs[3][4096];   // [buf][128 rows][32 k]

  const int nwg = gridDim.x * gridDim.y;   // 512
  const int fid = blockIdx.y * gridDim.x + blockIdx.x;
  const int lid = (fid & 7) * (nwg >> 3) + (fid >> 3);
  const int bx = lid % gridDim.x, by = lid / gridDim.x;

  const int tid  = threadIdx.x;
  const int lane = tid & 63;
  const int wid  = tid >> 6;
  const int wm = wid >> 2, wn = wid & 3;
  const int g4 = lane >> 4, r15 = lane & 15;
  const int m0 = by << 6, n0 = bx << 7;

  const int srow  = lane >> 2;
  const int sslot = lane & 3;
  const int arow  = (wid & 3) * 16 + srow;
  const int asw   = (arow ^ (arow >> 2)) & 3;
  const u16* gaP  = &A[(size_t)(m0 + arow) * 1024 + ((sslot ^ asw) << 3)];
  const int brow  = wid * 16 + srow;
  const int bsw   = (brow ^ (brow >> 2)) & 3;
  const u16* gbP  = &Bt[(size_t)(n0 + brow) * 1024 + ((sslot ^ bsw) << 3)];

  f32x4 acc[2][2] = {};

  auto stage_t = [&](int t, int buf) {
    if (wid < 4)
      gl2lds16(gaP + t * 32, (char*)As[buf] + (wid & 3) * 1024);
    gl2lds16(gbP + t * 32, (char*)Bs[buf] + wid * 1024);
  };
  auto compute_t = [&](int buf) {
    bf16x8 af[2], bfr[2];
#pragma unroll
    for (int m = 0; m < 2; m++) {
      int row = wm * 32 + m * 16 + r15;
      int sw = (row ^ (row >> 2)) & 3;
      af[m] = *reinterpret_cast<const bf16x8*>(
          (const char*)As[buf] + row * 64 + ((g4 ^ sw) << 4));
    }
#pragma unroll
    for (int n = 0; n < 2; n++) {
      int row = wn * 32 + n * 16 + r15;
      int sw = (row ^ (row >> 2)) & 3;
      bfr[n] = *reinterpret_cast<const bf16x8*>(
          (const char*)Bs[buf] + row * 64 + ((g4 ^ sw) << 4));
    }
#pragma unroll
    for (int m = 0; m < 2; m++)
#pragma unroll
      for (int n = 0; n < 2; n++)
        acc[m][n] = __builtin_amdgcn_mfma_f32_16x16x32_bf16(af[m], bfr[n], acc[m][n], 0, 0, 0);
  };

  stage_t(0, 0);
  stage_t(1, 1);

  int rd = 0, wr = 2;
#pragma unroll 1
  for (int t = 0; t < 30; ++t) {
    stage_t(t + 2, wr);
    if (wid < 4) { WAITV(4); } else { WAITV(2); }
    bar();
    compute_t(rd);
    bar();
    wr = rd;
    rd = (rd + 1 == 3) ? 0 : rd + 1;
  }
  if (wid < 4) { WAITV(2); } else { WAITV(1); }
  bar();
  compute_t(0);
  bar();
  WAITV(0);
  bar();
  compute_t(1);

  float bb[2] = {0.f, 0.f};
  if (BIAS) {
#pragma unroll
    for (int n = 0; n < 2; n++) bb[n] = bias[n0 + wn * 32 + n * 16 + r15];
  }

  if (RES) {
    float sc_[2], sh_[2];
    if (RESNORM) {
#pragma unroll
      for (int n = 0; n < 2; n++) {
        int col = n0 + wn * 32 + n * 16 + r15;
        sc_[n] = nsc[col];
        sh_[n] = nsh[col];
      }
    }
    float sp[2] = {0.f, 0.f}, sq[2] = {0.f, 0.f};
#pragma unroll
    for (int m = 0; m < 2; m++) {
      int row = m0 + wm * 32 + m * 16 + g4 * 4;
#pragma unroll
      for (int n = 0; n < 2; n++) {
        int col = n0 + wn * 32 + n * 16 + r15;
#pragma unroll
        for (int j = 0; j < 4; j++) {
          size_t off = (size_t)(row + j) * 1024 + col;
          float v = acc[m][n][j] + bb[n];
          float res = bf2f(RresB[off]);
          if (RESNORM) res = fmaf(res, sc_[n], sh_[n]);
          float r = v + res;
          Rout[off] = f2bf(r);
          sp[n] += r;
          sq[n] = fmaf(r, r, sq[n]);
        }
      }
    }
#pragma unroll
    for (int n = 0; n < 2; n++) {
      sp[n] += __shfl_xor(sp[n], 16, 64);
      sp[n] += __shfl_xor(sp[n], 32, 64);
      sq[n] += __shfl_xor(sq[n], 16, 64);
      sq[n] += __shfl_xor(sq[n], 32, 64);
    }
    if (g4 == 0) {
      int slot = (by << 1) + wm;               // 0..127
#pragma unroll
      for (int n = 0; n < 2; n++) {
        int col = n0 + wn * 32 + n * 16 + r15;
        psum[(size_t)slot * 1024 + col] = sp[n];
        psumsq[(size_t)slot * 1024 + col] = sq[n];
      }
    }
    return;
  }

#pragma unroll
  for (int m = 0; m < 2; m++) {
    int row = m0 + wm * 32 + m * 16 + g4 * 4;
#pragma unroll
    for (int n = 0; n < 2; n++) {
      int col = n0 + wn * 32 + n * 16 + r15;
#pragma unroll
      for (int j = 0; j < 4; j++) {
        float v = acc[m][n][j];
        if (BIAS) v += bb[n];
        if (RELU) v = fmaxf(v, 0.f);
        if (OUTM == 1) Cb[(size_t)(row + j) * 1024 + col] = f2bf(v);
      }
    }
  }
}

// ---------------------------------------------------------------------------
// Flash MFMA attention: dbuf K/V staging (counted vmcnt), defer-max (T13),
// setprio around MFMA clusters (T5, attn-verified m191).
// Grid (bh=128, qchunk=8); block = 64 q-rows (4 waves).
// ---------------------------------------------------------------------------
__global__ __launch_bounds__(256, 2) void attn_k(
    const u16* __restrict__ qk, const u16* __restrict__ Vt,
    u16* __restrict__ o)
{
  __shared__ __align__(16) unsigned char Ks[2][16384];
  __shared__ __align__(16) unsigned char Vs[2][16384];
  __shared__ __align__(16) unsigned char Ps[16384];

  const int bh  = blockIdx.x;
  const int qc  = blockIdx.y;
  const int b   = bh >> 4, h = bh & 15;
  const int tid = threadIdx.x;
  const int lane = tid & 63;
  const int wv   = tid >> 6;
  const int qcol = lane & 15;
  const int g    = lane >> 4;

  const size_t rowbase = (size_t)b * Tn;
  const size_t qrow0   = rowbase + qc * 64 + wv * 16;

  bf16x8 qf[2];
  {
    const u16* qp = &qk[(qrow0 + qcol) * 2048 + h * 64 + g * 8];
    qf[0] = *reinterpret_cast<const bf16x8*>(qp);
    qf[1] = *reinterpret_cast<const bf16x8*>(qp + 32);
  }

  f32x4 oa[4] = {};
  float m_run = -3e38f, l_run = 0.f;

  const int krow = tid >> 3, kch = tid & 7;
  const int vrow = tid >> 4, vch = tid & 15;
  unsigned char* Pw = &Ps[wv * 4096];

  auto stage_kv = [&](int c, int buf) {
#pragma unroll
    for (int i = 0; i < 4; i++) {
      int row = i * 32 + krow;
      const u16* gk = &qk[(rowbase + c * 128 + row) * 2048 + 1024 + h * 64
                          + ((kch ^ (row & 7)) << 3)];
      gl2lds16(gk, (char*)Ks[buf] + wv * 1024 + i * 4096);
    }
#pragma unroll
    for (int i = 0; i < 4; i++) {
      int row = i * 16 + vrow;
      const u16* gv = &Vt[(((size_t)bh * 64 + row) << 9) + c * 128
                          + ((vch ^ (row & 7)) << 3)];
      gl2lds16(gv, (char*)Vs[buf] + wv * 1024 + i * 4096);
    }
  };

  auto compute_c = [&](int cur) {
    f32x4 sf[8];
    __builtin_amdgcn_s_setprio(1);
#pragma unroll
    for (int t = 0; t < 8; t++) {
      sf[t] = (f32x4){0.f, 0.f, 0.f, 0.f};
      const int srow = t * 16 + qcol;
      const int base = srow * 128;
      const int sw = srow & 7;
#pragma unroll
      for (int ks = 0; ks < 2; ks++) {
        bf16x8 a = *reinterpret_cast<const bf16x8*>(
            &Ks[cur][base + (((ks * 4 + g) ^ sw) << 4)]);
        sf[t] = __builtin_amdgcn_mfma_f32_16x16x32_bf16(a, qf[ks], sf[t], 0, 0, 0);
      }
    }
    __builtin_amdgcn_s_setprio(0);

    float mc = -3e38f;
#pragma unroll
    for (int t = 0; t < 8; t++)
#pragma unroll
      for (int r = 0; r < 4; r++) {
        float s = sf[t][r] * 0.125f;
        sf[t][r] = s;
        mc = fmaxf(mc, s);
      }
    mc = fmaxf(mc, __shfl_xor(mc, 16, 64));
    mc = fmaxf(mc, __shfl_xor(mc, 32, 64));

    if (__all(mc - m_run <= 8.f)) {
      float lsum = 0.f;
#pragma unroll
      for (int t = 0; t < 8; t++)
#pragma unroll
        for (int r = 0; r < 4; r++) {
          float e = __expf(sf[t][r] - m_run);
          sf[t][r] = e;
          lsum += e;
        }
      lsum += __shfl_xor(lsum, 16, 64);
      lsum += __shfl_xor(lsum, 32, 64);
      l_run += lsum;
    } else {
      float mnew = fmaxf(m_run, mc);
      float alpha = __expf(m_run - mnew);
      m_run = mnew;
      float lsum = 0.f;
#pragma unroll
      for (int t = 0; t < 8; t++)
#pragma unroll
        for (int r = 0; r < 4; r++) {
          float e = __expf(sf[t][r] - mnew);
          sf[t][r] = e;
          lsum += e;
        }
      lsum += __shfl_xor(lsum, 16, 64);
      lsum += __shfl_xor(lsum, 32, 64);
      l_run = l_run * alpha + lsum;
#pragma unroll
      for (int j = 0; j < 4; j++) {
        float av = __shfl(alpha, (g << 4) + g * 4 + j, 64);
#pragma unroll
        for (int nt = 0; nt < 4; nt++) oa[nt][j] *= av;
      }
    }

#pragma unroll
    for (int t = 0; t < 8; t++) {
      int o0 = t * 32 + g * 8;
      int chunk = o0 >> 4;
      int sb = ((chunk ^ (qcol & 7)) << 4) | (o0 & 15);
      *reinterpret_cast<unsigned int*>(&Pw[qcol * 256 + sb]) =
          pack2bf(sf[t][0], sf[t][1]);
      *reinterpret_cast<unsigned int*>(&Pw[qcol * 256 + sb + 4]) =
          pack2bf(sf[t][2], sf[t][3]);
    }

    bf16x8 pa[4];
#pragma unroll
    for (int ks = 0; ks < 4; ks++)
      pa[ks] = *reinterpret_cast<const bf16x8*>(
          &Pw[qcol * 256 + (((ks * 4 + g) ^ (qcol & 7)) << 4)]);
    __builtin_amdgcn_s_setprio(1);
#pragma unroll
    for (int nt = 0; nt < 4; nt++) {
      const int vr = nt * 16 + qcol;
      const int vsw = vr & 7;
#pragma unroll
      for (int ks = 0; ks < 4; ks++) {
        bf16x8 bvf = *reinterpret_cast<const bf16x8*>(
            &Vs[cur][vr * 256 + (((ks * 4 + g) ^ vsw) << 4)]);
        oa[nt] = __builtin_amdgcn_mfma_f32_16x16x32_bf16(pa[ks], bvf, oa[nt], 0, 0, 0);
      }
    }
    __builtin_amdgcn_s_setprio(0);
  };

  stage_kv(0, 0);
#pragma unroll 1
  for (int c = 0; c < 3; ++c) {
    stage_kv(c + 1, (c + 1) & 1);
    WAITV(8);
    bar();
    compute_c(c & 1);
    bar();
  }
  WAITV(0);
  bar();
  compute_c(1);

  float rl = 1.f / l_run;
#pragma unroll
  for (int j = 0; j < 4; j++) {
    float il = __shfl(rl, (g << 4) + g * 4 + j, 64);
#pragma unroll
    for (int nt = 0; nt < 4; nt++)
      o[(qrow0 + g * 4 + j) * 1024 + h * 64 + nt * 16 + qcol] =
          f2bf(oa[nt][j] * il);
  }
}

// ---------------------------------------------------------------------------
// reduce 128 partial col sums -> scale/shift. 32 blocks x 32 cols, LDS tree.
// ---------------------------------------------------------------------------
__global__ __launch_bounds__(256) void reduce_stats_k(
    const float* __restrict__ ps, const float* __restrict__ pq,
    const float* __restrict__ g, const float* __restrict__ be,
    float* __restrict__ scale, float* __restrict__ shift)
{
  __shared__ float Ls[8][32], Lq[8][32];
  const int t = threadIdx.x;
  const int col = blockIdx.x * 32 + (t & 31);
  const int rg = t >> 5;
  float s = 0.f, q = 0.f;
#pragma unroll
  for (int i = 0; i < 16; i++) {
    int p = rg * 16 + i;
    s += ps[(size_t)p * Dn + col];
    q += pq[(size_t)p * Dn + col];
  }
  Ls[rg][t & 31] = s;
  Lq[rg][t & 31] = q;
  __syncthreads();
  if (t < 32) {
    float S = 0.f, Q = 0.f;
#pragma unroll
    for (int r = 0; r < 8; r++) { S += Ls[r][t]; Q += Lq[r][t]; }
    const float invn = 1.f / 4096.f;
    float mean = S * invn;
    float var = Q * invn - mean * mean;
    float inv = rsqrtf(var + 1e-3f);
    float sc = g[col] * inv;
    scale[col] = sc;
    shift[col] = be[col] - mean * sc;
  }
}

// BN apply on bf16 residual stream. OUTMODE: 0 = fp32 out, 2 = bf16 out.
template<int OUTMODE>
__global__ __launch_bounds__(256) void norm_k(
    const u16* __restrict__ r, const float* __restrict__ scale,
    const float* __restrict__ shift, float* __restrict__ o, u16* __restrict__ ob)
{
  const size_t i8 = ((size_t)blockIdx.x * 256 + threadIdx.x) * 8;
  const int col = (int)(i8 & 1023);
  uint4 rv = *reinterpret_cast<const uint4*>(&r[i8]);
  const u16* rs = reinterpret_cast<const u16*>(&rv);
  float4 sc0 = *reinterpret_cast<const float4*>(&scale[col]);
  float4 sc1 = *reinterpret_cast<const float4*>(&scale[col + 4]);
  float4 sh0 = *reinterpret_cast<const float4*>(&shift[col]);
  float4 sh1 = *reinterpret_cast<const float4*>(&shift[col + 4]);
  const float scs[8] = {sc0.x, sc0.y, sc0.z, sc0.w, sc1.x, sc1.y, sc1.z, sc1.w};
  const float shs[8] = {sh0.x, sh0.y, sh0.z, sh0.w, sh1.x, sh1.y, sh1.z, sh1.w};
  float v[8];
#pragma unroll
  for (int j = 0; j < 8; j++)
    v[j] = fmaf(bf2f(rs[j]), scs[j], shs[j]);
  if (OUTMODE == 0) {
    float4 o0 = make_float4(v[0], v[1], v[2], v[3]);
    float4 o1 = make_float4(v[4], v[5], v[6], v[7]);
    *reinterpret_cast<float4*>(&o[i8]) = o0;
    *reinterpret_cast<float4*>(&o[i8 + 4]) = o1;
  } else {
    uint4 p;
    p.x = pack2bf(v[0], v[1]); p.y = pack2bf(v[2], v[3]);
    p.z = pack2bf(v[4], v[5]); p.w = pack2bf(v[6], v[7]);
    *reinterpret_cast<uint4*>(&ob[i8]) = p;
  }
}

// ---------------------------------------------------------------------------
extern "C" void kernel_launch(void* const* d_in, const int* in_sizes, int n_in,
                              void* d_out, int out_size, void* d_ws, size_t ws_size,
                              hipStream_t stream)
{
  const float* x   = (const float*)d_in[0];
  const float* wq  = (const float*)d_in[1];
  const float* wk  = (const float*)d_in[2];
  const float* wv  = (const float*)d_in[3];
  const float* W   = (const float*)d_in[4];
  const float* W1  = (const float*)d_in[5];
  const float* b1  = (const float*)d_in[6];
  const float* W2  = (const float*)d_in[7];
  const float* b2  = (const float*)d_in[8];
  const float* g1  = (const float*)d_in[9];
  const float* be1 = (const float*)d_in[10];
  const float* g2  = (const float*)d_in[11];
  const float* be2 = (const float*)d_in[12];

  float* out = (float*)d_out;
  float* ws  = (float*)d_ws;

  const size_t NB = (size_t)Mn * Dn;   // 4M
  float* psum   = ws;                  // 128*1024
  float* psumsq = psum + 128 * Dn;
  float* scale1 = psumsq + 128 * Dn;
  float* shift1 = scale1 + Dn;
  float* scale2 = shift1 + Dn;
  float* shift2 = scale2 + Dn;
  u16* ws1b    = (u16*)(shift2 + Dn);  // 4M u16: r1 bf16
  u16* ws2b    = ws1b + NB;            // 4M u16: r2 bf16
  u16* xb      = ws2b + NB;            // 4M
  u16* qkb     = xb + NB;              // 8M  [4096][2048]
  u16* vtb     = qkb + 2 * NB;         // 4M  [(b,h)][64][512]
  u16* concatb = vtb + NB;             // 4M
  u16* wqkvT   = concatb + NB;         // 3M
  u16* wt      = wqkvT + 3 * 1048576;
  u16* w1t     = wt + 1048576;
  u16* w2t     = w1t + 1048576;
  // aliases (qkb dead after attn):
  u16* out1b = qkb;
  u16* hb    = qkb + NB;

  dim3 b256(256), b512(512);

  // 0. prep
  prep_k<<<dim3(3584), b256, 0, stream>>>(x, xb, wq, wk, wv, wqkvT,
                                          W, W1, W2, wt, w1t, w2t);
  // 1. qkv = x @ [Wq|Wk|Wv]; q,k -> qkb (ldc 2048), V -> vtb transposed
  mgemm_k<1><<<dim3(24, 32), b512, 0, stream>>>(xb, wqkvT, qkb, 2048, vtb);
  // 2. flash attention -> concat bf16
  attn_k<<<dim3(128, 8), b256, 0, stream>>>(qkb, vtb, concatb);
  // 3. r1 = x + concat @ W -> ws1b bf16 (+stats fused; residual = xb bf16)
  mgemm64_k<0, 0, 2, 1, 0><<<dim3(8, 64), b512, 0, stream>>>(
      concatb, wt, nullptr, nullptr, xb, ws1b, psum, psumsq,
      nullptr, nullptr);
  reduce_stats_k<<<dim3(32), b256, 0, stream>>>(psum, psumsq, g1, be1, scale1, shift1);
  // 4. out1b = BN1(r1) bf16
  norm_k<2><<<dim3(2048), b256, 0, stream>>>(ws1b, scale1, shift1, nullptr, out1b);
  // 5. h = relu(out1 @ W1 + b1) -> bf16
  mgemm64_k<1, 1, 1, 0, 0><<<dim3(8, 64), b512, 0, stream>>>(
      out1b, w1t, b1, hb, nullptr, nullptr, nullptr, nullptr,
      nullptr, nullptr);
  // 6. r2 = BN1(r1) + (h @ W2 + b2) -> ws2b bf16 (+stats fused)
  mgemm64_k<1, 0, 2, 1, 1><<<dim3(8, 64), b512, 0, stream>>>(
      hb, w2t, b2, nullptr, ws1b, ws2b, psum, psumsq,
      scale1, shift1);
  reduce_stats_k<<<dim3(32), b256, 0, stream>>>(psum, psumsq, g2, be2, scale2, shift2);
  // 7. final BN -> d_out (fp32)
  norm_k<0><<<dim3(2048), b256, 0, stream>>>(ws2b, scale2, shift2, out, nullptr);
}

// Round 15
// 142.639 us; speedup vs baseline: 1.0153x; 1.0153x over previous
//
#include <hip/hip_runtime.h>
#include <hip/hip_bf16.h>
#include <cstdint>

#define Bn 8
#define Tn 512
#define Dn 1024
#define Hn 16
#define DKn 64
#define Mn (Bn * Tn)   // 4096

typedef unsigned short u16;
typedef short bf16x8 __attribute__((ext_vector_type(8)));
typedef float f32x4 __attribute__((ext_vector_type(4)));

__device__ __forceinline__ u16 f2bf(float f) {
  unsigned int u = __builtin_bit_cast(unsigned int, f);
  u += 0x7fffu + ((u >> 16) & 1u);
  return (u16)(u >> 16);
}
__device__ __forceinline__ float bf2f(u16 v) {
  return __builtin_bit_cast(float, (unsigned int)v << 16);
}
__device__ __forceinline__ unsigned int pack2bf(float lo, float hi) {
  return (unsigned int)f2bf(lo) | ((unsigned int)f2bf(hi) << 16);
}

// async global->LDS, 16B per lane; lds ptr wave-uniform + lane*16.
__device__ __forceinline__ void gl2lds16(const void* g, void* l) {
  __builtin_amdgcn_global_load_lds(
      (const __attribute__((address_space(1))) unsigned int*)g,
      (__attribute__((address_space(3))) unsigned int*)l,
      16, 0, 0);
}

// raw workgroup barrier: compiler memory fence only (no sched pin — m141).
__device__ __forceinline__ void bar() {
  asm volatile("" ::: "memory");
  __builtin_amdgcn_s_barrier();
  asm volatile("" ::: "memory");
}
#define WAITV(n_) asm volatile("s_waitcnt vmcnt(" #n_ ")" ::: "memory")

// ---------------------------------------------------------------------------
// prep: x->bf16, QKV weight transpose, W transposes (one dispatcher kernel).
// ---------------------------------------------------------------------------
__global__ __launch_bounds__(256) void prep_k(
    const float* __restrict__ x, u16* __restrict__ xb,
    const float* __restrict__ wq, const float* __restrict__ wk,
    const float* __restrict__ wv, u16* __restrict__ wqkvT,
    const float* __restrict__ W, const float* __restrict__ W1,
    const float* __restrict__ W2, u16* __restrict__ wt,
    u16* __restrict__ w1t, u16* __restrict__ w2t)
{
  const int bid = blockIdx.x;
  const int t = threadIdx.x;
  if (bid < 2048) {
    const size_t i = ((size_t)bid * 256 + t) * 8;
    float4 a = *reinterpret_cast<const float4*>(&x[i]);
    float4 b = *reinterpret_cast<const float4*>(&x[i + 4]);
    uint4 w;
    w.x = pack2bf(a.x, a.y); w.y = pack2bf(a.z, a.w);
    w.z = pack2bf(b.x, b.y); w.w = pack2bf(b.z, b.w);
    *reinterpret_cast<uint4*>(&xb[i]) = w;
  } else if (bid < 2816) {
    const int idx = bid - 2048;
    const int kt = idx & 15;
    const int y  = idx >> 4;
    const int tau = y >> 4, head = y & 15;
    const float* src = (tau == 0 ? wq : tau == 1 ? wk : wv) + (size_t)head * 65536;
    const int n  = t & 63;
    const int kq = (t >> 6) << 4;
    const int k0 = kt << 6;
    u16 v[16];
#pragma unroll
    for (int j = 0; j < 16; j++)
      v[j] = f2bf(src[(size_t)(k0 + kq + j) * 64 + n]);
    u16* d = &wqkvT[((size_t)tau * 1024 + head * 64 + n) * 1024 + k0 + kq];
    *reinterpret_cast<uint4*>(&d[0]) = *reinterpret_cast<uint4*>(&v[0]);
    *reinterpret_cast<uint4*>(&d[8]) = *reinterpret_cast<uint4*>(&v[8]);
  } else {
    const int idx = bid - 2816;
    const int kt = idx & 15;
    const int rest = idx >> 4;
    const int ntl = rest & 15, z = rest >> 4;
    const float* src = (z == 0 ? W : z == 1 ? W1 : W2);
    u16* dst = (z == 0 ? wt : z == 1 ? w1t : w2t);
    const int n  = (ntl << 6) + (t & 63);
    const int kq = (t >> 6) << 4;
    const int k0 = kt << 6;
    u16 v[16];
#pragma unroll
    for (int j = 0; j < 16; j++)
      v[j] = f2bf(src[(size_t)(k0 + kq + j) * 1024 + n]);
    u16* d = &dst[(size_t)n * 1024 + k0 + kq];
    *reinterpret_cast<uint4*>(&d[0]) = *reinterpret_cast<uint4*>(&v[0]);
    *reinterpret_cast<uint4*>(&d[8]) = *reinterpret_cast<uint4*>(&v[8]);
  }
}

// ---------------------------------------------------------------------------
// Big-grid bf16 MFMA GEMM (QKV): tile 128x128, BK=32, 512 thr = 8 waves 2x4,
// wave-tile 64x32. RING-2 LDS, 1-deep prefetch with counted vmcnt + raw
// barrier pair per K-step (verified-safe; single-barrier raced — round 13).
// VT: blocks bx>=16 write V transposed via LDS transpose (coalesced 64B runs).
// ---------------------------------------------------------------------------
template<int VT>
__global__ __launch_bounds__(512) void mgemm_k(
    const u16* __restrict__ A, const u16* __restrict__ Bt,
    u16* __restrict__ Cb, int ldc, u16* __restrict__ Vt)
{
  __shared__ __align__(16) u16 As[2][4480];   // buf stride 8960B; tile uses 8192B
  __shared__ __align__(16) u16 Bs[2][4480];

  const int nwg = gridDim.x * gridDim.y;
  const int fid = blockIdx.y * gridDim.x + blockIdx.x;
  const int lid = (fid & 7) * (nwg >> 3) + (fid >> 3);
  const int bx = lid % gridDim.x, by = lid / gridDim.x;

  const int tid  = threadIdx.x;
  const int lane = tid & 63;
  const int wid  = tid >> 6;
  const int wm = wid >> 2, wn = wid & 3;
  const int g4 = lane >> 4, r15 = lane & 15;
  const int m0 = by << 7, n0 = bx << 7;

  const int srow  = tid >> 2;
  const int sslot = tid & 3;
  const int ssw   = (srow ^ (srow >> 2)) & 3;
  const int sk8   = ((sslot ^ ssw) << 3);
  const u16* ga0 = &A[(size_t)(m0 + srow) * 1024 + sk8];
  const u16* gb0 = &Bt[(size_t)(n0 + srow) * 1024 + sk8];
  const int lofs = wid * 1024;

  f32x4 acc[4][2] = {};

  auto stage_t = [&](int t, int buf) {
    gl2lds16(ga0 + t * 32, (char*)As[buf] + lofs);
    gl2lds16(gb0 + t * 32, (char*)Bs[buf] + lofs);
  };
  auto compute_t = [&](int buf) {
    bf16x8 af[4], bfr[2];
#pragma unroll
    for (int m = 0; m < 4; m++) {
      int row = wm * 64 + m * 16 + r15;
      int sw = (row ^ (row >> 2)) & 3;
      af[m] = *reinterpret_cast<const bf16x8*>(
          (const char*)As[buf] + row * 64 + ((g4 ^ sw) << 4));
    }
#pragma unroll
    for (int n = 0; n < 2; n++) {
      int row = wn * 32 + n * 16 + r15;
      int sw = (row ^ (row >> 2)) & 3;
      bfr[n] = *reinterpret_cast<const bf16x8*>(
          (const char*)Bs[buf] + row * 64 + ((g4 ^ sw) << 4));
    }
#pragma unroll
    for (int m = 0; m < 4; m++)
#pragma unroll
      for (int n = 0; n < 2; n++)
        acc[m][n] = __builtin_amdgcn_mfma_f32_16x16x32_bf16(af[m], bfr[n], acc[m][n], 0, 0, 0);
  };

  stage_t(0, 0);
#pragma unroll 1
  for (int t = 0; t < 31; ++t) {
    stage_t(t + 1, (t + 1) & 1);   // 4 in flight
    WAITV(2);                      // tile t landed; t+1 stays in flight
    bar();
    compute_t(t & 1);
    bar();                         // all waves done reading buf t&1
  }
  WAITV(0);
  bar();
  compute_t(1);

  if (VT && bx >= 16) {
    bar();   // all waves done reading compute LDS
    const int vcol0 = n0 - 2048;
#pragma unroll
    for (int m = 0; m < 4; m++) {
      int sloc = wm * 64 + m * 16 + g4 * 4;
#pragma unroll
      for (int n = 0; n < 2; n++) {
        int cv = wn * 32 + n * 16 + r15;
        u16* base = (cv < 64) ? (u16*)As : (u16*)Bs;
        uint2 pk;
        pk.x = pack2bf(acc[m][n][0], acc[m][n][1]);
        pk.y = pack2bf(acc[m][n][2], acc[m][n][3]);
        *reinterpret_cast<uint2*>(&base[(size_t)(cv & 63) * 136 + sloc]) = pk;
      }
    }
    bar();
    {
      int cv = tid >> 2;                 // 0..127
      int sch = (tid & 3) << 5;          // 0,32,64,96
      const u16* base = (cv < 64) ? (const u16*)As : (const u16*)Bs;
      const u16* src = &base[(size_t)(cv & 63) * 136 + sch];
      uint4 v0 = *reinterpret_cast<const uint4*>(src);
      uint4 v1 = *reinterpret_cast<const uint4*>(src + 8);
      uint4 v2 = *reinterpret_cast<const uint4*>(src + 16);
      uint4 v3 = *reinterpret_cast<const uint4*>(src + 24);
      int vcol = vcol0 + cv;
      int hh = vcol >> 6, dk = vcol & 63;
      int bI = m0 >> 9, sbase = (m0 & 511) + sch;
      u16* dst = &Vt[(((size_t)(bI * 16 + hh) * 64 + dk) << 9) + sbase];
      *reinterpret_cast<uint4*>(dst) = v0;
      *reinterpret_cast<uint4*>(dst + 8) = v1;
      *reinterpret_cast<uint4*>(dst + 16) = v2;
      *reinterpret_cast<uint4*>(dst + 24) = v3;
    }
    return;
  }

#pragma unroll
  for (int m = 0; m < 4; m++) {
    int row = m0 + wm * 64 + m * 16 + g4 * 4;
#pragma unroll
    for (int n = 0; n < 2; n++) {
      int col = n0 + wn * 32 + n * 16 + r15;
#pragma unroll
      for (int j = 0; j < 4; j++)
        Cb[(size_t)(row + j) * ldc + col] = f2bf(acc[m][n][j]);
    }
  }
}

// ---------------------------------------------------------------------------
// Small-N bf16 MFMA GEMM (proj/FFN, N=1024): tile 64x128, grid (8,64)=512
// blocks, 512 thr = 8 waves 2x4, wave-tile 32x32. Ring-3 LDS, 2-deep
// prefetch, counted vmcnt, two barriers per K-step (verified-safe).
// OUTM: 1=bf16 C, 2=none. RES: r=acc(+bias)+res(bf16) -> Rout(bf16) + stats.
// RESNORM: res = BN(RresB) on the fly (scale/shift per col).
// ---------------------------------------------------------------------------
template<int BIAS, int RELU, int OUTM, int RES, int RESNORM>
__global__ __launch_bounds__(512) void mgemm64_k(
    const u16* __restrict__ A, const u16* __restrict__ Bt,
    const float* __restrict__ bias, u16* __restrict__ Cb,
    const u16* __restrict__ RresB, u16* __restrict__ Rout,
    float* __restrict__ psum, float* __restrict__ psumsq,
    const float* __restrict__ nsc, const float* __restrict__ nsh)
{
  __shared__ __align__(16) u16 As[3][2048];   // [buf][64 rows][32 k]
  __shared__ __align__(16) u16 Bs[3][4096];   // [buf][128 rows][32 k]

  const int nwg = gridDim.x * gridDim.y;   // 512
  const int fid = blockIdx.y * gridDim.x + blockIdx.x;
  const int lid = (fid & 7) * (nwg >> 3) + (fid >> 3);
  const int bx = lid % gridDim.x, by = lid / gridDim.x;

  const int tid  = threadIdx.x;
  const int lane = tid & 63;
  const int wid  = tid >> 6;
  const int wm = wid >> 2, wn = wid & 3;
  const int g4 = lane >> 4, r15 = lane & 15;
  const int m0 = by << 6, n0 = bx << 7;

  const int srow  = lane >> 2;
  const int sslot = lane & 3;
  const int arow  = (wid & 3) * 16 + srow;
  const int asw   = (arow ^ (arow >> 2)) & 3;
  const u16* gaP  = &A[(size_t)(m0 + arow) * 1024 + ((sslot ^ asw) << 3)];
  const int brow  = wid * 16 + srow;
  const int bsw   = (brow ^ (brow >> 2)) & 3;
  const u16* gbP  = &Bt[(size_t)(n0 + brow) * 1024 + ((sslot ^ bsw) << 3)];

  f32x4 acc[2][2] = {};

  auto stage_t = [&](int t, int buf) {
    if (wid < 4)
      gl2lds16(gaP + t * 32, (char*)As[buf] + (wid & 3) * 1024);
    gl2lds16(gbP + t * 32, (char*)Bs[buf] + wid * 1024);
  };
  auto compute_t = [&](int buf) {
    bf16x8 af[2], bfr[2];
#pragma unroll
    for (int m = 0; m < 2; m++) {
      int row = wm * 32 + m * 16 + r15;
      int sw = (row ^ (row >> 2)) & 3;
      af[m] = *reinterpret_cast<const bf16x8*>(
          (const char*)As[buf] + row * 64 + ((g4 ^ sw) << 4));
    }
#pragma unroll
    for (int n = 0; n < 2; n++) {
      int row = wn * 32 + n * 16 + r15;
      int sw = (row ^ (row >> 2)) & 3;
      bfr[n] = *reinterpret_cast<const bf16x8*>(
          (const char*)Bs[buf] + row * 64 + ((g4 ^ sw) << 4));
    }
#pragma unroll
    for (int m = 0; m < 2; m++)
#pragma unroll
      for (int n = 0; n < 2; n++)
        acc[m][n] = __builtin_amdgcn_mfma_f32_16x16x32_bf16(af[m], bfr[n], acc[m][n], 0, 0, 0);
  };

  stage_t(0, 0);
  stage_t(1, 1);

  int rd = 0, wr = 2;
#pragma unroll 1
  for (int t = 0; t < 30; ++t) {
    stage_t(t + 2, wr);
    if (wid < 4) { WAITV(4); } else { WAITV(2); }
    bar();
    compute_t(rd);
    bar();
    wr = rd;
    rd = (rd + 1 == 3) ? 0 : rd + 1;
  }
  if (wid < 4) { WAITV(2); } else { WAITV(1); }
  bar();
  compute_t(0);
  bar();
  WAITV(0);
  bar();
  compute_t(1);

  float bb[2] = {0.f, 0.f};
  if (BIAS) {
#pragma unroll
    for (int n = 0; n < 2; n++) bb[n] = bias[n0 + wn * 32 + n * 16 + r15];
  }

  if (RES) {
    float sc_[2], sh_[2];
    if (RESNORM) {
#pragma unroll
      for (int n = 0; n < 2; n++) {
        int col = n0 + wn * 32 + n * 16 + r15;
        sc_[n] = nsc[col];
        sh_[n] = nsh[col];
      }
    }
    float sp[2] = {0.f, 0.f}, sq[2] = {0.f, 0.f};
#pragma unroll
    for (int m = 0; m < 2; m++) {
      int row = m0 + wm * 32 + m * 16 + g4 * 4;
#pragma unroll
      for (int n = 0; n < 2; n++) {
        int col = n0 + wn * 32 + n * 16 + r15;
#pragma unroll
        for (int j = 0; j < 4; j++) {
          size_t off = (size_t)(row + j) * 1024 + col;
          float v = acc[m][n][j] + bb[n];
          float res = bf2f(RresB[off]);
          if (RESNORM) res = fmaf(res, sc_[n], sh_[n]);
          float r = v + res;
          Rout[off] = f2bf(r);
          sp[n] += r;
          sq[n] = fmaf(r, r, sq[n]);
        }
      }
    }
#pragma unroll
    for (int n = 0; n < 2; n++) {
      sp[n] += __shfl_xor(sp[n], 16, 64);
      sp[n] += __shfl_xor(sp[n], 32, 64);
      sq[n] += __shfl_xor(sq[n], 16, 64);
      sq[n] += __shfl_xor(sq[n], 32, 64);
    }
    if (g4 == 0) {
      int slot = (by << 1) + wm;               // 0..127
#pragma unroll
      for (int n = 0; n < 2; n++) {
        int col = n0 + wn * 32 + n * 16 + r15;
        psum[(size_t)slot * 1024 + col] = sp[n];
        psumsq[(size_t)slot * 1024 + col] = sq[n];
      }
    }
    return;
  }

#pragma unroll
  for (int m = 0; m < 2; m++) {
    int row = m0 + wm * 32 + m * 16 + g4 * 4;
#pragma unroll
    for (int n = 0; n < 2; n++) {
      int col = n0 + wn * 32 + n * 16 + r15;
#pragma unroll
      for (int j = 0; j < 4; j++) {
        float v = acc[m][n][j];
        if (BIAS) v += bb[n];
        if (RELU) v = fmaxf(v, 0.f);
        if (OUTM == 1) Cb[(size_t)(row + j) * 1024 + col] = f2bf(v);
      }
    }
  }
}

// ---------------------------------------------------------------------------
// Flash MFMA attention, KVBLK=64: LDS 40KB (Ks 16K + Vs 16K + Ps 8K) ->
// 4 blocks/CU (was 80KB -> 2). Same verified dbuf 2-barrier ring-2 schedule,
// 8 chunks of 64 s-rows. defer-max (T13) + setprio (T5).
// Grid (bh=128, qchunk=8); block = 64 q-rows (4 waves).
// ---------------------------------------------------------------------------
__global__ __launch_bounds__(256, 4) void attn_k(
    const u16* __restrict__ qk, const u16* __restrict__ Vt,
    u16* __restrict__ o)
{
  __shared__ __align__(16) unsigned char Ks[2][8192];   // [64 s][128B dk] swz
  __shared__ __align__(16) unsigned char Vs[2][8192];   // [64 dk][128B s] swz
  __shared__ __align__(16) unsigned char Ps[8192];      // per-wave [16 q][128B s]

  const int bh  = blockIdx.x;
  const int qc  = blockIdx.y;
  const int b   = bh >> 4, h = bh & 15;
  const int tid = threadIdx.x;
  const int lane = tid & 63;
  const int wv   = tid >> 6;
  const int qcol = lane & 15;
  const int g    = lane >> 4;

  const size_t rowbase = (size_t)b * Tn;
  const size_t qrow0   = rowbase + qc * 64 + wv * 16;

  bf16x8 qf[2];
  {
    const u16* qp = &qk[(qrow0 + qcol) * 2048 + h * 64 + g * 8];
    qf[0] = *reinterpret_cast<const bf16x8*>(qp);
    qf[1] = *reinterpret_cast<const bf16x8*>(qp + 32);
  }

  f32x4 oa[4] = {};
  float m_run = -3e38f, l_run = 0.f;

  const int srw = tid >> 3;           // 0..31 (row within a 32-row issue)
  const int sch = tid & 7;            // 16B chunk
  unsigned char* Pw = &Ps[wv * 2048];

  auto stage_kv = [&](int c, int buf) {
#pragma unroll
    for (int i = 0; i < 2; i++) {
      int row = i * 32 + srw;
      const u16* gk = &qk[(rowbase + c * 64 + row) * 2048 + 1024 + h * 64
                          + ((sch ^ (row & 7)) << 3)];
      gl2lds16(gk, (char*)Ks[buf] + wv * 1024 + i * 4096);
    }
#pragma unroll
    for (int i = 0; i < 2; i++) {
      int row = i * 32 + srw;         // dk row
      const u16* gv = &Vt[(((size_t)bh * 64 + row) << 9) + c * 64
                          + ((sch ^ (row & 7)) << 3)];
      gl2lds16(gv, (char*)Vs[buf] + wv * 1024 + i * 4096);
    }
  };

  auto compute_c = [&](int cur) {
    // ---- QK^T: 4 S^T tiles (64 s-rows x 16 q-cols) ----
    f32x4 sf[4];
    __builtin_amdgcn_s_setprio(1);
#pragma unroll
    for (int t = 0; t < 4; t++) {
      sf[t] = (f32x4){0.f, 0.f, 0.f, 0.f};
      const int srow = t * 16 + qcol;
      const int base = srow * 128;
      const int sw = srow & 7;
#pragma unroll
      for (int ks = 0; ks < 2; ks++) {
        bf16x8 a = *reinterpret_cast<const bf16x8*>(
            &Ks[cur][base + (((ks * 4 + g) ^ sw) << 4)]);
        sf[t] = __builtin_amdgcn_mfma_f32_16x16x32_bf16(a, qf[ks], sf[t], 0, 0, 0);
      }
    }
    __builtin_amdgcn_s_setprio(0);

    // ---- online softmax (row = this lane's qcol) ----
    float mc = -3e38f;
#pragma unroll
    for (int t = 0; t < 4; t++)
#pragma unroll
      for (int r = 0; r < 4; r++) {
        float s = sf[t][r] * 0.125f;
        sf[t][r] = s;
        mc = fmaxf(mc, s);
      }
    mc = fmaxf(mc, __shfl_xor(mc, 16, 64));
    mc = fmaxf(mc, __shfl_xor(mc, 32, 64));

    if (__all(mc - m_run <= 8.f)) {   // T13 defer-max
      float lsum = 0.f;
#pragma unroll
      for (int t = 0; t < 4; t++)
#pragma unroll
        for (int r = 0; r < 4; r++) {
          float e = __expf(sf[t][r] - m_run);
          sf[t][r] = e;
          lsum += e;
        }
      lsum += __shfl_xor(lsum, 16, 64);
      lsum += __shfl_xor(lsum, 32, 64);
      l_run += lsum;
    } else {
      float mnew = fmaxf(m_run, mc);
      float alpha = __expf(m_run - mnew);
      m_run = mnew;
      float lsum = 0.f;
#pragma unroll
      for (int t = 0; t < 4; t++)
#pragma unroll
        for (int r = 0; r < 4; r++) {
          float e = __expf(sf[t][r] - mnew);
          sf[t][r] = e;
          lsum += e;
        }
      lsum += __shfl_xor(lsum, 16, 64);
      lsum += __shfl_xor(lsum, 32, 64);
      l_run = l_run * alpha + lsum;
#pragma unroll
      for (int j = 0; j < 4; j++) {
        float av = __shfl(alpha, (g << 4) + g * 4 + j, 64);
#pragma unroll
        for (int nt = 0; nt < 4; nt++) oa[nt][j] *= av;
      }
    }

    // ---- pack P -> per-wave LDS (swizzled), wave-coherent ----
#pragma unroll
    for (int t = 0; t < 4; t++) {
      int o0 = t * 32 + g * 8;          // byte offset of s = t*16 + g*4
      int chunk = o0 >> 4;              // 0..7
      int sb = ((chunk ^ (qcol & 7)) << 4) | (o0 & 15);
      *reinterpret_cast<unsigned int*>(&Pw[qcol * 128 + sb]) =
          pack2bf(sf[t][0], sf[t][1]);
      *reinterpret_cast<unsigned int*>(&Pw[qcol * 128 + sb + 4]) =
          pack2bf(sf[t][2], sf[t][3]);
    }

    // ---- PV ----
    bf16x8 pa[2];
#pragma unroll
    for (int ks = 0; ks < 2; ks++)
      pa[ks] = *reinterpret_cast<const bf16x8*>(
          &Pw[qcol * 128 + (((ks * 4 + g) ^ (qcol & 7)) << 4)]);
    __builtin_amdgcn_s_setprio(1);
#pragma unroll
    for (int nt = 0; nt < 4; nt++) {
      const int vr = nt * 16 + qcol;
      const int vsw = vr & 7;
#pragma unroll
      for (int ks = 0; ks < 2; ks++) {
        bf16x8 bvf = *reinterpret_cast<const bf16x8*>(
            &Vs[cur][vr * 128 + (((ks * 4 + g) ^ vsw) << 4)]);
        oa[nt] = __builtin_amdgcn_mfma_f32_16x16x32_bf16(pa[ks], bvf, oa[nt], 0, 0, 0);
      }
    }
    __builtin_amdgcn_s_setprio(0);
  };

  stage_kv(0, 0);
#pragma unroll 1
  for (int c = 0; c < 7; ++c) {
    stage_kv(c + 1, (c + 1) & 1);   // +4 -> 8 in flight
    WAITV(4);                       // chunk c landed; c+1 stays in flight
    bar();
    compute_c(c & 1);
    bar();                          // all waves done with buf c&1
  }
  WAITV(0);
  bar();
  compute_c(1);

  float rl = 1.f / l_run;
#pragma unroll
  for (int j = 0; j < 4; j++) {
    float il = __shfl(rl, (g << 4) + g * 4 + j, 64);
#pragma unroll
    for (int nt = 0; nt < 4; nt++)
      o[(qrow0 + g * 4 + j) * 1024 + h * 64 + nt * 16 + qcol] =
          f2bf(oa[nt][j] * il);
  }
}

// ---------------------------------------------------------------------------
// reduce 128 partial col sums -> scale/shift. 32 blocks x 32 cols, LDS tree.
// ---------------------------------------------------------------------------
__global__ __launch_bounds__(256) void reduce_stats_k(
    const float* __restrict__ ps, const float* __restrict__ pq,
    const float* __restrict__ g, const float* __restrict__ be,
    float* __restrict__ scale, float* __restrict__ shift)
{
  __shared__ float Ls[8][32], Lq[8][32];
  const int t = threadIdx.x;
  const int col = blockIdx.x * 32 + (t & 31);
  const int rg = t >> 5;
  float s = 0.f, q = 0.f;
#pragma unroll
  for (int i = 0; i < 16; i++) {
    int p = rg * 16 + i;
    s += ps[(size_t)p * Dn + col];
    q += pq[(size_t)p * Dn + col];
  }
  Ls[rg][t & 31] = s;
  Lq[rg][t & 31] = q;
  __syncthreads();
  if (t < 32) {
    float S = 0.f, Q = 0.f;
#pragma unroll
    for (int r = 0; r < 8; r++) { S += Ls[r][t]; Q += Lq[r][t]; }
    const float invn = 1.f / 4096.f;
    float mean = S * invn;
    float var = Q * invn - mean * mean;
    float inv = rsqrtf(var + 1e-3f);
    float sc = g[col] * inv;
    scale[col] = sc;
    shift[col] = be[col] - mean * sc;
  }
}

// BN apply on bf16 residual stream. OUTMODE: 0 = fp32 out, 2 = bf16 out.
template<int OUTMODE>
__global__ __launch_bounds__(256) void norm_k(
    const u16* __restrict__ r, const float* __restrict__ scale,
    const float* __restrict__ shift, float* __restrict__ o, u16* __restrict__ ob)
{
  const size_t i8 = ((size_t)blockIdx.x * 256 + threadIdx.x) * 8;
  const int col = (int)(i8 & 1023);
  uint4 rv = *reinterpret_cast<const uint4*>(&r[i8]);
  const u16* rs = reinterpret_cast<const u16*>(&rv);
  float4 sc0 = *reinterpret_cast<const float4*>(&scale[col]);
  float4 sc1 = *reinterpret_cast<const float4*>(&scale[col + 4]);
  float4 sh0 = *reinterpret_cast<const float4*>(&shift[col]);
  float4 sh1 = *reinterpret_cast<const float4*>(&shift[col + 4]);
  const float scs[8] = {sc0.x, sc0.y, sc0.z, sc0.w, sc1.x, sc1.y, sc1.z, sc1.w};
  const float shs[8] = {sh0.x, sh0.y, sh0.z, sh0.w, sh1.x, sh1.y, sh1.z, sh1.w};
  float v[8];
#pragma unroll
  for (int j = 0; j < 8; j++)
    v[j] = fmaf(bf2f(rs[j]), scs[j], shs[j]);
  if (OUTMODE == 0) {
    float4 o0 = make_float4(v[0], v[1], v[2], v[3]);
    float4 o1 = make_float4(v[4], v[5], v[6], v[7]);
    *reinterpret_cast<float4*>(&o[i8]) = o0;
    *reinterpret_cast<float4*>(&o[i8 + 4]) = o1;
  } else {
    uint4 p;
    p.x = pack2bf(v[0], v[1]); p.y = pack2bf(v[2], v[3]);
    p.z = pack2bf(v[4], v[5]); p.w = pack2bf(v[6], v[7]);
    *reinterpret_cast<uint4*>(&ob[i8]) = p;
  }
}

// ---------------------------------------------------------------------------
extern "C" void kernel_launch(void* const* d_in, const int* in_sizes, int n_in,
                              void* d_out, int out_size, void* d_ws, size_t ws_size,
                              hipStream_t stream)
{
  const float* x   = (const float*)d_in[0];
  const float* wq  = (const float*)d_in[1];
  const float* wk  = (const float*)d_in[2];
  const float* wv  = (const float*)d_in[3];
  const float* W   = (const float*)d_in[4];
  const float* W1  = (const float*)d_in[5];
  const float* b1  = (const float*)d_in[6];
  const float* W2  = (const float*)d_in[7];
  const float* b2  = (const float*)d_in[8];
  const float* g1  = (const float*)d_in[9];
  const float* be1 = (const float*)d_in[10];
  const float* g2  = (const float*)d_in[11];
  const float* be2 = (const float*)d_in[12];

  float* out = (float*)d_out;
  float* ws  = (float*)d_ws;

  const size_t NB = (size_t)Mn * Dn;   // 4M
  float* psum   = ws;                  // 128*1024
  float* psumsq = psum + 128 * Dn;
  float* scale1 = psumsq + 128 * Dn;
  float* shift1 = scale1 + Dn;
  float* scale2 = shift1 + Dn;
  float* shift2 = scale2 + Dn;
  u16* ws1b    = (u16*)(shift2 + Dn);  // 4M u16: r1 bf16
  u16* ws2b    = ws1b + NB;            // 4M u16: r2 bf16
  u16* xb      = ws2b + NB;            // 4M
  u16* qkb     = xb + NB;              // 8M  [4096][2048]
  u16* vtb     = qkb + 2 * NB;         // 4M  [(b,h)][64][512]
  u16* concatb = vtb + NB;             // 4M
  u16* wqkvT   = concatb + NB;         // 3M
  u16* wt      = wqkvT + 3 * 1048576;
  u16* w1t     = wt + 1048576;
  u16* w2t     = w1t + 1048576;
  // aliases (qkb dead after attn):
  u16* out1b = qkb;
  u16* hb    = qkb + NB;

  dim3 b256(256), b512(512);

  // 0. prep
  prep_k<<<dim3(3584), b256, 0, stream>>>(x, xb, wq, wk, wv, wqkvT,
                                          W, W1, W2, wt, w1t, w2t);
  // 1. qkv = x @ [Wq|Wk|Wv]; q,k -> qkb (ldc 2048), V -> vtb transposed
  mgemm_k<1><<<dim3(24, 32), b512, 0, stream>>>(xb, wqkvT, qkb, 2048, vtb);
  // 2. flash attention -> concat bf16
  attn_k<<<dim3(128, 8), b256, 0, stream>>>(qkb, vtb, concatb);
  // 3. r1 = x + concat @ W -> ws1b bf16 (+stats fused; residual = xb bf16)
  mgemm64_k<0, 0, 2, 1, 0><<<dim3(8, 64), b512, 0, stream>>>(
      concatb, wt, nullptr, nullptr, xb, ws1b, psum, psumsq,
      nullptr, nullptr);
  reduce_stats_k<<<dim3(32), b256, 0, stream>>>(psum, psumsq, g1, be1, scale1, shift1);
  // 4. out1b = BN1(r1) bf16
  norm_k<2><<<dim3(2048), b256, 0, stream>>>(ws1b, scale1, shift1, nullptr, out1b);
  // 5. h = relu(out1 @ W1 + b1) -> bf16
  mgemm64_k<1, 1, 1, 0, 0><<<dim3(8, 64), b512, 0, stream>>>(
      out1b, w1t, b1, hb, nullptr, nullptr, nullptr, nullptr,
      nullptr, nullptr);
  // 6. r2 = BN1(r1) + (h @ W2 + b2) -> ws2b bf16 (+stats fused)
  mgemm64_k<1, 0, 2, 1, 1><<<dim3(8, 64), b512, 0, stream>>>(
      hb, w2t, b2, nullptr, ws1b, ws2b, psum, psumsq,
      scale1, shift1);
  reduce_stats_k<<<dim3(32), b256, 0, stream>>>(psum, psumsq, g2, be2, scale2, shift2);
  // 7. final BN -> d_out (fp32)
  norm_k<0><<<dim3(2048), b256, 0, stream>>>(ws2b, scale2, shift2, out, nullptr);
}

// Round 16
// 141.157 us; speedup vs baseline: 1.0260x; 1.0105x over previous
//
#include <hip/hip_runtime.h>
#include <hip/hip_bf16.h>
#include <cstdint>

#define Bn 8
#define Tn 512
#define Dn 1024
#define Hn 16
#define DKn 64
#define Mn (Bn * Tn)   // 4096

typedef unsigned short u16;
typedef short bf16x8 __attribute__((ext_vector_type(8)));
typedef float f32x4 __attribute__((ext_vector_type(4)));

__device__ __forceinline__ u16 f2bf(float f) {
  unsigned int u = __builtin_bit_cast(unsigned int, f);
  u += 0x7fffu + ((u >> 16) & 1u);
  return (u16)(u >> 16);
}
__device__ __forceinline__ float bf2f(u16 v) {
  return __builtin_bit_cast(float, (unsigned int)v << 16);
}
__device__ __forceinline__ unsigned int pack2bf(float lo, float hi) {
  return (unsigned int)f2bf(lo) | ((unsigned int)f2bf(hi) << 16);
}

// async global->LDS, 16B per lane; lds ptr wave-uniform + lane*16.
__device__ __forceinline__ void gl2lds16(const void* g, void* l) {
  __builtin_amdgcn_global_load_lds(
      (const __attribute__((address_space(1))) unsigned int*)g,
      (__attribute__((address_space(3))) unsigned int*)l,
      16, 0, 0);
}

// raw workgroup barrier: compiler memory fence only (no sched pin — m141).
__device__ __forceinline__ void bar() {
  asm volatile("" ::: "memory");
  __builtin_amdgcn_s_barrier();
  asm volatile("" ::: "memory");
}
#define WAITV(n_) asm volatile("s_waitcnt vmcnt(" #n_ ")" ::: "memory")

// ---------------------------------------------------------------------------
// prep: x->bf16, QKV weight transpose, W transposes (one dispatcher kernel).
// ---------------------------------------------------------------------------
__global__ __launch_bounds__(256) void prep_k(
    const float* __restrict__ x, u16* __restrict__ xb,
    const float* __restrict__ wq, const float* __restrict__ wk,
    const float* __restrict__ wv, u16* __restrict__ wqkvT,
    const float* __restrict__ W, const float* __restrict__ W1,
    const float* __restrict__ W2, u16* __restrict__ wt,
    u16* __restrict__ w1t, u16* __restrict__ w2t)
{
  const int bid = blockIdx.x;
  const int t = threadIdx.x;
  if (bid < 2048) {
    const size_t i = ((size_t)bid * 256 + t) * 8;
    float4 a = *reinterpret_cast<const float4*>(&x[i]);
    float4 b = *reinterpret_cast<const float4*>(&x[i + 4]);
    uint4 w;
    w.x = pack2bf(a.x, a.y); w.y = pack2bf(a.z, a.w);
    w.z = pack2bf(b.x, b.y); w.w = pack2bf(b.z, b.w);
    *reinterpret_cast<uint4*>(&xb[i]) = w;
  } else if (bid < 2816) {
    const int idx = bid - 2048;
    const int kt = idx & 15;
    const int y  = idx >> 4;
    const int tau = y >> 4, head = y & 15;
    const float* src = (tau == 0 ? wq : tau == 1 ? wk : wv) + (size_t)head * 65536;
    const int n  = t & 63;
    const int kq = (t >> 6) << 4;
    const int k0 = kt << 6;
    u16 v[16];
#pragma unroll
    for (int j = 0; j < 16; j++)
      v[j] = f2bf(src[(size_t)(k0 + kq + j) * 64 + n]);
    u16* d = &wqkvT[((size_t)tau * 1024 + head * 64 + n) * 1024 + k0 + kq];
    *reinterpret_cast<uint4*>(&d[0]) = *reinterpret_cast<uint4*>(&v[0]);
    *reinterpret_cast<uint4*>(&d[8]) = *reinterpret_cast<uint4*>(&v[8]);
  } else {
    const int idx = bid - 2816;
    const int kt = idx & 15;
    const int rest = idx >> 4;
    const int ntl = rest & 15, z = rest >> 4;
    const float* src = (z == 0 ? W : z == 1 ? W1 : W2);
    u16* dst = (z == 0 ? wt : z == 1 ? w1t : w2t);
    const int n  = (ntl << 6) + (t & 63);
    const int kq = (t >> 6) << 4;
    const int k0 = kt << 6;
    u16 v[16];
#pragma unroll
    for (int j = 0; j < 16; j++)
      v[j] = f2bf(src[(size_t)(k0 + kq + j) * 1024 + n]);
    u16* d = &dst[(size_t)n * 1024 + k0 + kq];
    *reinterpret_cast<uint4*>(&d[0]) = *reinterpret_cast<uint4*>(&v[0]);
    *reinterpret_cast<uint4*>(&d[8]) = *reinterpret_cast<uint4*>(&v[8]);
  }
}

// ---------------------------------------------------------------------------
// Big-grid bf16 MFMA GEMM (QKV): tile 128x128, BK=32, 512 thr = 8 waves 2x4,
// wave-tile 64x32. RING-2 LDS, 1-deep prefetch with counted vmcnt + raw
// barrier pair per K-step (verified-safe; single-barrier raced — round 13).
// VT: blocks bx>=16 write V transposed via LDS transpose (coalesced 64B runs).
// ---------------------------------------------------------------------------
template<int VT>
__global__ __launch_bounds__(512) void mgemm_k(
    const u16* __restrict__ A, const u16* __restrict__ Bt,
    u16* __restrict__ Cb, int ldc, u16* __restrict__ Vt)
{
  __shared__ __align__(16) u16 As[2][4480];   // buf stride 8960B; tile uses 8192B
  __shared__ __align__(16) u16 Bs[2][4480];

  const int nwg = gridDim.x * gridDim.y;
  const int fid = blockIdx.y * gridDim.x + blockIdx.x;
  const int lid = (fid & 7) * (nwg >> 3) + (fid >> 3);
  const int bx = lid % gridDim.x, by = lid / gridDim.x;

  const int tid  = threadIdx.x;
  const int lane = tid & 63;
  const int wid  = tid >> 6;
  const int wm = wid >> 2, wn = wid & 3;
  const int g4 = lane >> 4, r15 = lane & 15;
  const int m0 = by << 7, n0 = bx << 7;

  const int srow  = tid >> 2;
  const int sslot = tid & 3;
  const int ssw   = (srow ^ (srow >> 2)) & 3;
  const int sk8   = ((sslot ^ ssw) << 3);
  const u16* ga0 = &A[(size_t)(m0 + srow) * 1024 + sk8];
  const u16* gb0 = &Bt[(size_t)(n0 + srow) * 1024 + sk8];
  const int lofs = wid * 1024;

  f32x4 acc[4][2] = {};

  auto stage_t = [&](int t, int buf) {
    gl2lds16(ga0 + t * 32, (char*)As[buf] + lofs);
    gl2lds16(gb0 + t * 32, (char*)Bs[buf] + lofs);
  };
  auto compute_t = [&](int buf) {
    bf16x8 af[4], bfr[2];
#pragma unroll
    for (int m = 0; m < 4; m++) {
      int row = wm * 64 + m * 16 + r15;
      int sw = (row ^ (row >> 2)) & 3;
      af[m] = *reinterpret_cast<const bf16x8*>(
          (const char*)As[buf] + row * 64 + ((g4 ^ sw) << 4));
    }
#pragma unroll
    for (int n = 0; n < 2; n++) {
      int row = wn * 32 + n * 16 + r15;
      int sw = (row ^ (row >> 2)) & 3;
      bfr[n] = *reinterpret_cast<const bf16x8*>(
          (const char*)Bs[buf] + row * 64 + ((g4 ^ sw) << 4));
    }
#pragma unroll
    for (int m = 0; m < 4; m++)
#pragma unroll
      for (int n = 0; n < 2; n++)
        acc[m][n] = __builtin_amdgcn_mfma_f32_16x16x32_bf16(af[m], bfr[n], acc[m][n], 0, 0, 0);
  };

  stage_t(0, 0);
#pragma unroll 1
  for (int t = 0; t < 31; ++t) {
    stage_t(t + 1, (t + 1) & 1);   // 4 in flight
    WAITV(2);                      // tile t landed; t+1 stays in flight
    bar();
    compute_t(t & 1);
    bar();                         // all waves done reading buf t&1
  }
  WAITV(0);
  bar();
  compute_t(1);

  if (VT && bx >= 16) {
    bar();   // all waves done reading compute LDS
    const int vcol0 = n0 - 2048;
#pragma unroll
    for (int m = 0; m < 4; m++) {
      int sloc = wm * 64 + m * 16 + g4 * 4;
#pragma unroll
      for (int n = 0; n < 2; n++) {
        int cv = wn * 32 + n * 16 + r15;
        u16* base = (cv < 64) ? (u16*)As : (u16*)Bs;
        uint2 pk;
        pk.x = pack2bf(acc[m][n][0], acc[m][n][1]);
        pk.y = pack2bf(acc[m][n][2], acc[m][n][3]);
        *reinterpret_cast<uint2*>(&base[(size_t)(cv & 63) * 136 + sloc]) = pk;
      }
    }
    bar();
    {
      int cv = tid >> 2;                 // 0..127
      int sch = (tid & 3) << 5;          // 0,32,64,96
      const u16* base = (cv < 64) ? (const u16*)As : (const u16*)Bs;
      const u16* src = &base[(size_t)(cv & 63) * 136 + sch];
      uint4 v0 = *reinterpret_cast<const uint4*>(src);
      uint4 v1 = *reinterpret_cast<const uint4*>(src + 8);
      uint4 v2 = *reinterpret_cast<const uint4*>(src + 16);
      uint4 v3 = *reinterpret_cast<const uint4*>(src + 24);
      int vcol = vcol0 + cv;
      int hh = vcol >> 6, dk = vcol & 63;
      int bI = m0 >> 9, sbase = (m0 & 511) + sch;
      u16* dst = &Vt[(((size_t)(bI * 16 + hh) * 64 + dk) << 9) + sbase];
      *reinterpret_cast<uint4*>(dst) = v0;
      *reinterpret_cast<uint4*>(dst + 8) = v1;
      *reinterpret_cast<uint4*>(dst + 16) = v2;
      *reinterpret_cast<uint4*>(dst + 24) = v3;
    }
    return;
  }

#pragma unroll
  for (int m = 0; m < 4; m++) {
    int row = m0 + wm * 64 + m * 16 + g4 * 4;
#pragma unroll
    for (int n = 0; n < 2; n++) {
      int col = n0 + wn * 32 + n * 16 + r15;
#pragma unroll
      for (int j = 0; j < 4; j++)
        Cb[(size_t)(row + j) * ldc + col] = f2bf(acc[m][n][j]);
    }
  }
}

// ---------------------------------------------------------------------------
// Small-N bf16 MFMA GEMM (proj/FFN, N=1024): tile 64x128, grid (8,64)=512
// blocks, 512 thr = 8 waves 2x4, wave-tile 32x32. Ring-3 LDS, 2-deep
// prefetch, counted vmcnt, two barriers per K-step (verified-safe).
// OUTM: 1=bf16 C, 2=none. RES: r=acc(+bias)+res(bf16) -> Rout(bf16) + stats.
// RESNORM: res = BN(RresB) on the fly (scale/shift per col).
// ---------------------------------------------------------------------------
template<int BIAS, int RELU, int OUTM, int RES, int RESNORM>
__global__ __launch_bounds__(512) void mgemm64_k(
    const u16* __restrict__ A, const u16* __restrict__ Bt,
    const float* __restrict__ bias, u16* __restrict__ Cb,
    const u16* __restrict__ RresB, u16* __restrict__ Rout,
    float* __restrict__ psum, float* __restrict__ psumsq,
    const float* __restrict__ nsc, const float* __restrict__ nsh)
{
  __shared__ __align__(16) u16 As[3][2048];   // [buf][64 rows][32 k]
  __shared__ __align__(16) u16 Bs[3][4096];   // [buf][128 rows][32 k]

  const int nwg = gridDim.x * gridDim.y;   // 512
  const int fid = blockIdx.y * gridDim.x + blockIdx.x;
  const int lid = (fid & 7) * (nwg >> 3) + (fid >> 3);
  const int bx = lid % gridDim.x, by = lid / gridDim.x;

  const int tid  = threadIdx.x;
  const int lane = tid & 63;
  const int wid  = tid >> 6;
  const int wm = wid >> 2, wn = wid & 3;
  const int g4 = lane >> 4, r15 = lane & 15;
  const int m0 = by << 6, n0 = bx << 7;

  const int srow  = lane >> 2;
  const int sslot = lane & 3;
  const int arow  = (wid & 3) * 16 + srow;
  const int asw   = (arow ^ (arow >> 2)) & 3;
  const u16* gaP  = &A[(size_t)(m0 + arow) * 1024 + ((sslot ^ asw) << 3)];
  const int brow  = wid * 16 + srow;
  const int bsw   = (brow ^ (brow >> 2)) & 3;
  const u16* gbP  = &Bt[(size_t)(n0 + brow) * 1024 + ((sslot ^ bsw) << 3)];

  f32x4 acc[2][2] = {};

  auto stage_t = [&](int t, int buf) {
    if (wid < 4)
      gl2lds16(gaP + t * 32, (char*)As[buf] + (wid & 3) * 1024);
    gl2lds16(gbP + t * 32, (char*)Bs[buf] + wid * 1024);
  };
  auto compute_t = [&](int buf) {
    bf16x8 af[2], bfr[2];
#pragma unroll
    for (int m = 0; m < 2; m++) {
      int row = wm * 32 + m * 16 + r15;
      int sw = (row ^ (row >> 2)) & 3;
      af[m] = *reinterpret_cast<const bf16x8*>(
          (const char*)As[buf] + row * 64 + ((g4 ^ sw) << 4));
    }
#pragma unroll
    for (int n = 0; n < 2; n++) {
      int row = wn * 32 + n * 16 + r15;
      int sw = (row ^ (row >> 2)) & 3;
      bfr[n] = *reinterpret_cast<const bf16x8*>(
          (const char*)Bs[buf] + row * 64 + ((g4 ^ sw) << 4));
    }
#pragma unroll
    for (int m = 0; m < 2; m++)
#pragma unroll
      for (int n = 0; n < 2; n++)
        acc[m][n] = __builtin_amdgcn_mfma_f32_16x16x32_bf16(af[m], bfr[n], acc[m][n], 0, 0, 0);
  };

  stage_t(0, 0);
  stage_t(1, 1);

  int rd = 0, wr = 2;
#pragma unroll 1
  for (int t = 0; t < 30; ++t) {
    stage_t(t + 2, wr);
    if (wid < 4) { WAITV(4); } else { WAITV(2); }
    bar();
    compute_t(rd);
    bar();
    wr = rd;
    rd = (rd + 1 == 3) ? 0 : rd + 1;
  }
  if (wid < 4) { WAITV(2); } else { WAITV(1); }
  bar();
  compute_t(0);
  bar();
  WAITV(0);
  bar();
  compute_t(1);

  float bb[2] = {0.f, 0.f};
  if (BIAS) {
#pragma unroll
    for (int n = 0; n < 2; n++) bb[n] = bias[n0 + wn * 32 + n * 16 + r15];
  }

  if (RES) {
    float sc_[2], sh_[2];
    if (RESNORM) {
#pragma unroll
      for (int n = 0; n < 2; n++) {
        int col = n0 + wn * 32 + n * 16 + r15;
        sc_[n] = nsc[col];
        sh_[n] = nsh[col];
      }
    }
    float sp[2] = {0.f, 0.f}, sq[2] = {0.f, 0.f};
#pragma unroll
    for (int m = 0; m < 2; m++) {
      int row = m0 + wm * 32 + m * 16 + g4 * 4;
#pragma unroll
      for (int n = 0; n < 2; n++) {
        int col = n0 + wn * 32 + n * 16 + r15;
#pragma unroll
        for (int j = 0; j < 4; j++) {
          size_t off = (size_t)(row + j) * 1024 + col;
          float v = acc[m][n][j] + bb[n];
          float res = bf2f(RresB[off]);
          if (RESNORM) res = fmaf(res, sc_[n], sh_[n]);
          float r = v + res;
          Rout[off] = f2bf(r);
          sp[n] += r;
          sq[n] = fmaf(r, r, sq[n]);
        }
      }
    }
#pragma unroll
    for (int n = 0; n < 2; n++) {
      sp[n] += __shfl_xor(sp[n], 16, 64);
      sp[n] += __shfl_xor(sp[n], 32, 64);
      sq[n] += __shfl_xor(sq[n], 16, 64);
      sq[n] += __shfl_xor(sq[n], 32, 64);
    }
    if (g4 == 0) {
      int slot = (by << 1) + wm;               // 0..127
#pragma unroll
      for (int n = 0; n < 2; n++) {
        int col = n0 + wn * 32 + n * 16 + r15;
        psum[(size_t)slot * 1024 + col] = sp[n];
        psumsq[(size_t)slot * 1024 + col] = sq[n];
      }
    }
    return;
  }

#pragma unroll
  for (int m = 0; m < 2; m++) {
    int row = m0 + wm * 32 + m * 16 + g4 * 4;
#pragma unroll
    for (int n = 0; n < 2; n++) {
      int col = n0 + wn * 32 + n * 16 + r15;
#pragma unroll
      for (int j = 0; j < 4; j++) {
        float v = acc[m][n][j];
        if (BIAS) v += bb[n];
        if (RELU) v = fmaxf(v, 0.f);
        if (OUTM == 1) Cb[(size_t)(row + j) * 1024 + col] = f2bf(v);
      }
    }
  }
}

// ---------------------------------------------------------------------------
// Flash MFMA attention, 128 q-rows/block (8 waves, 512 thr), KVBLK=64.
// Staging: ONE K + ONE V issue per thread per chunk (halved vs 64-row
// blocks); K/V HBM re-fetch halves (4 blocks per (b,h) instead of 8).
// LDS 48KB (Ks 2x8K + Vs 2x8K + Ps 8x2K). Same verified 2-barrier dbuf
// ring-2 schedule, 8 chunks. defer-max (T13) + setprio (T5).
// Grid (bh=128, qchunk=4).
// ---------------------------------------------------------------------------
__global__ __launch_bounds__(512) void attn_k(
    const u16* __restrict__ qk, const u16* __restrict__ Vt,
    u16* __restrict__ o)
{
  __shared__ __align__(16) unsigned char Ks[2][8192];   // [64 s][128B dk] swz
  __shared__ __align__(16) unsigned char Vs[2][8192];   // [64 dk][128B s] swz
  __shared__ __align__(16) unsigned char Ps[16384];     // per-wave [16 q][128B s]

  const int bh  = blockIdx.x;
  const int qc  = blockIdx.y;          // 0..3 (128-row q chunk)
  const int b   = bh >> 4, h = bh & 15;
  const int tid = threadIdx.x;
  const int lane = tid & 63;
  const int wv   = tid >> 6;           // 0..7
  const int qcol = lane & 15;
  const int g    = lane >> 4;

  const size_t rowbase = (size_t)b * Tn;
  const size_t qrow0   = rowbase + qc * 128 + wv * 16;

  bf16x8 qf[2];
  {
    const u16* qp = &qk[(qrow0 + qcol) * 2048 + h * 64 + g * 8];
    qf[0] = *reinterpret_cast<const bf16x8*>(qp);
    qf[1] = *reinterpret_cast<const bf16x8*>(qp + 32);
  }

  f32x4 oa[4] = {};
  float m_run = -3e38f, l_run = 0.f;

  const int srw = tid >> 3;            // 0..63 (s-row / dk-row)
  const int sch = tid & 7;             // 16B chunk within row
  unsigned char* Pw = &Ps[wv * 2048];

  auto stage_kv = [&](int c, int buf) {
    // K chunk [64 s][64 dk]: one issue per thread, dest = linear tid*16
    const u16* gk = &qk[(rowbase + c * 64 + srw) * 2048 + 1024 + h * 64
                        + ((sch ^ (srw & 7)) << 3)];
    gl2lds16(gk, (char*)Ks[buf] + wv * 1024);
    // V^T chunk [64 dk][64 s]: one issue per thread
    const u16* gv = &Vt[(((size_t)bh * 64 + srw) << 9) + c * 64
                        + ((sch ^ (srw & 7)) << 3)];
    gl2lds16(gv, (char*)Vs[buf] + wv * 1024);
  };

  auto compute_c = [&](int cur) {
    // ---- QK^T: 4 S^T tiles (64 s-rows x 16 q-cols) ----
    f32x4 sf[4];
    __builtin_amdgcn_s_setprio(1);
#pragma unroll
    for (int t = 0; t < 4; t++) {
      sf[t] = (f32x4){0.f, 0.f, 0.f, 0.f};
      const int srow = t * 16 + qcol;
      const int base = srow * 128;
      const int sw = srow & 7;
#pragma unroll
      for (int ks = 0; ks < 2; ks++) {
        bf16x8 a = *reinterpret_cast<const bf16x8*>(
            &Ks[cur][base + (((ks * 4 + g) ^ sw) << 4)]);
        sf[t] = __builtin_amdgcn_mfma_f32_16x16x32_bf16(a, qf[ks], sf[t], 0, 0, 0);
      }
    }
    __builtin_amdgcn_s_setprio(0);

    // ---- online softmax (row = this lane's qcol) ----
    float mc = -3e38f;
#pragma unroll
    for (int t = 0; t < 4; t++)
#pragma unroll
      for (int r = 0; r < 4; r++) {
        float s = sf[t][r] * 0.125f;
        sf[t][r] = s;
        mc = fmaxf(mc, s);
      }
    mc = fmaxf(mc, __shfl_xor(mc, 16, 64));
    mc = fmaxf(mc, __shfl_xor(mc, 32, 64));

    if (__all(mc - m_run <= 8.f)) {   // T13 defer-max
      float lsum = 0.f;
#pragma unroll
      for (int t = 0; t < 4; t++)
#pragma unroll
        for (int r = 0; r < 4; r++) {
          float e = __expf(sf[t][r] - m_run);
          sf[t][r] = e;
          lsum += e;
        }
      lsum += __shfl_xor(lsum, 16, 64);
      lsum += __shfl_xor(lsum, 32, 64);
      l_run += lsum;
    } else {
      float mnew = fmaxf(m_run, mc);
      float alpha = __expf(m_run - mnew);
      m_run = mnew;
      float lsum = 0.f;
#pragma unroll
      for (int t = 0; t < 4; t++)
#pragma unroll
        for (int r = 0; r < 4; r++) {
          float e = __expf(sf[t][r] - mnew);
          sf[t][r] = e;
          lsum += e;
        }
      lsum += __shfl_xor(lsum, 16, 64);
      lsum += __shfl_xor(lsum, 32, 64);
      l_run = l_run * alpha + lsum;
#pragma unroll
      for (int j = 0; j < 4; j++) {
        float av = __shfl(alpha, (g << 4) + g * 4 + j, 64);
#pragma unroll
        for (int nt = 0; nt < 4; nt++) oa[nt][j] *= av;
      }
    }

    // ---- pack P -> per-wave LDS (swizzled), wave-coherent ----
#pragma unroll
    for (int t = 0; t < 4; t++) {
      int o0 = t * 32 + g * 8;          // byte offset of s = t*16 + g*4
      int chunk = o0 >> 4;              // 0..7
      int sb = ((chunk ^ (qcol & 7)) << 4) | (o0 & 15);
      *reinterpret_cast<unsigned int*>(&Pw[qcol * 128 + sb]) =
          pack2bf(sf[t][0], sf[t][1]);
      *reinterpret_cast<unsigned int*>(&Pw[qcol * 128 + sb + 4]) =
          pack2bf(sf[t][2], sf[t][3]);
    }

    // ---- PV ----
    bf16x8 pa[2];
#pragma unroll
    for (int ks = 0; ks < 2; ks++)
      pa[ks] = *reinterpret_cast<const bf16x8*>(
          &Pw[qcol * 128 + (((ks * 4 + g) ^ (qcol & 7)) << 4)]);
    __builtin_amdgcn_s_setprio(1);
#pragma unroll
    for (int nt = 0; nt < 4; nt++) {
      const int vr = nt * 16 + qcol;
      const int vsw = vr & 7;
#pragma unroll
      for (int ks = 0; ks < 2; ks++) {
        bf16x8 bvf = *reinterpret_cast<const bf16x8*>(
            &Vs[cur][vr * 128 + (((ks * 4 + g) ^ vsw) << 4)]);
        oa[nt] = __builtin_amdgcn_mfma_f32_16x16x32_bf16(pa[ks], bvf, oa[nt], 0, 0, 0);
      }
    }
    __builtin_amdgcn_s_setprio(0);
  };

  stage_kv(0, 0);
#pragma unroll 1
  for (int c = 0; c < 7; ++c) {
    stage_kv(c + 1, (c + 1) & 1);   // +2 -> 4 in flight
    WAITV(2);                       // chunk c landed; c+1 stays in flight
    bar();
    compute_c(c & 1);
    bar();                          // all waves done with buf c&1
  }
  WAITV(0);
  bar();
  compute_c(1);

  float rl = 1.f / l_run;
#pragma unroll
  for (int j = 0; j < 4; j++) {
    float il = __shfl(rl, (g << 4) + g * 4 + j, 64);
#pragma unroll
    for (int nt = 0; nt < 4; nt++)
      o[(qrow0 + g * 4 + j) * 1024 + h * 64 + nt * 16 + qcol] =
          f2bf(oa[nt][j] * il);
  }
}

// ---------------------------------------------------------------------------
// reduce 128 partial col sums -> scale/shift. 32 blocks x 32 cols, LDS tree.
// ---------------------------------------------------------------------------
__global__ __launch_bounds__(256) void reduce_stats_k(
    const float* __restrict__ ps, const float* __restrict__ pq,
    const float* __restrict__ g, const float* __restrict__ be,
    float* __restrict__ scale, float* __restrict__ shift)
{
  __shared__ float Ls[8][32], Lq[8][32];
  const int t = threadIdx.x;
  const int col = blockIdx.x * 32 + (t & 31);
  const int rg = t >> 5;
  float s = 0.f, q = 0.f;
#pragma unroll
  for (int i = 0; i < 16; i++) {
    int p = rg * 16 + i;
    s += ps[(size_t)p * Dn + col];
    q += pq[(size_t)p * Dn + col];
  }
  Ls[rg][t & 31] = s;
  Lq[rg][t & 31] = q;
  __syncthreads();
  if (t < 32) {
    float S = 0.f, Q = 0.f;
#pragma unroll
    for (int r = 0; r < 8; r++) { S += Ls[r][t]; Q += Lq[r][t]; }
    const float invn = 1.f / 4096.f;
    float mean = S * invn;
    float var = Q * invn - mean * mean;
    float inv = rsqrtf(var + 1e-3f);
    float sc = g[col] * inv;
    scale[col] = sc;
    shift[col] = be[col] - mean * sc;
  }
}

// BN apply on bf16 residual stream. OUTMODE: 0 = fp32 out, 2 = bf16 out.
template<int OUTMODE>
__global__ __launch_bounds__(256) void norm_k(
    const u16* __restrict__ r, const float* __restrict__ scale,
    const float* __restrict__ shift, float* __restrict__ o, u16* __restrict__ ob)
{
  const size_t i8 = ((size_t)blockIdx.x * 256 + threadIdx.x) * 8;
  const int col = (int)(i8 & 1023);
  uint4 rv = *reinterpret_cast<const uint4*>(&r[i8]);
  const u16* rs = reinterpret_cast<const u16*>(&rv);
  float4 sc0 = *reinterpret_cast<const float4*>(&scale[col]);
  float4 sc1 = *reinterpret_cast<const float4*>(&scale[col + 4]);
  float4 sh0 = *reinterpret_cast<const float4*>(&shift[col]);
  float4 sh1 = *reinterpret_cast<const float4*>(&shift[col + 4]);
  const float scs[8] = {sc0.x, sc0.y, sc0.z, sc0.w, sc1.x, sc1.y, sc1.z, sc1.w};
  const float shs[8] = {sh0.x, sh0.y, sh0.z, sh0.w, sh1.x, sh1.y, sh1.z, sh1.w};
  float v[8];
#pragma unroll
  for (int j = 0; j < 8; j++)
    v[j] = fmaf(bf2f(rs[j]), scs[j], shs[j]);
  if (OUTMODE == 0) {
    float4 o0 = make_float4(v[0], v[1], v[2], v[3]);
    float4 o1 = make_float4(v[4], v[5], v[6], v[7]);
    *reinterpret_cast<float4*>(&o[i8]) = o0;
    *reinterpret_cast<float4*>(&o[i8 + 4]) = o1;
  } else {
    uint4 p;
    p.x = pack2bf(v[0], v[1]); p.y = pack2bf(v[2], v[3]);
    p.z = pack2bf(v[4], v[5]); p.w = pack2bf(v[6], v[7]);
    *reinterpret_cast<uint4*>(&ob[i8]) = p;
  }
}

// ---------------------------------------------------------------------------
extern "C" void kernel_launch(void* const* d_in, const int* in_sizes, int n_in,
                              void* d_out, int out_size, void* d_ws, size_t ws_size,
                              hipStream_t stream)
{
  const float* x   = (const float*)d_in[0];
  const float* wq  = (const float*)d_in[1];
  const float* wk  = (const float*)d_in[2];
  const float* wv  = (const float*)d_in[3];
  const float* W   = (const float*)d_in[4];
  const float* W1  = (const float*)d_in[5];
  const float* b1  = (const float*)d_in[6];
  const float* W2  = (const float*)d_in[7];
  const float* b2  = (const float*)d_in[8];
  const float* g1  = (const float*)d_in[9];
  const float* be1 = (const float*)d_in[10];
  const float* g2  = (const float*)d_in[11];
  const float* be2 = (const float*)d_in[12];

  float* out = (float*)d_out;
  float* ws  = (float*)d_ws;

  const size_t NB = (size_t)Mn * Dn;   // 4M
  float* psum   = ws;                  // 128*1024
  float* psumsq = psum + 128 * Dn;
  float* scale1 = psumsq + 128 * Dn;
  float* shift1 = scale1 + Dn;
  float* scale2 = shift1 + Dn;
  float* shift2 = scale2 + Dn;
  u16* ws1b    = (u16*)(shift2 + Dn);  // 4M u16: r1 bf16
  u16* ws2b    = ws1b + NB;            // 4M u16: r2 bf16
  u16* xb      = ws2b + NB;            // 4M
  u16* qkb     = xb + NB;              // 8M  [4096][2048]
  u16* vtb     = qkb + 2 * NB;         // 4M  [(b,h)][64][512]
  u16* concatb = vtb + NB;             // 4M
  u16* wqkvT   = concatb + NB;         // 3M
  u16* wt      = wqkvT + 3 * 1048576;
  u16* w1t     = wt + 1048576;
  u16* w2t     = w1t + 1048576;
  // aliases (qkb dead after attn):
  u16* out1b = qkb;
  u16* hb    = qkb + NB;

  dim3 b256(256), b512(512);

  // 0. prep
  prep_k<<<dim3(3584), b256, 0, stream>>>(x, xb, wq, wk, wv, wqkvT,
                                          W, W1, W2, wt, w1t, w2t);
  // 1. qkv = x @ [Wq|Wk|Wv]; q,k -> qkb (ldc 2048), V -> vtb transposed
  mgemm_k<1><<<dim3(24, 32), b512, 0, stream>>>(xb, wqkvT, qkb, 2048, vtb);
  // 2. flash attention -> concat bf16 (128 q-rows/block)
  attn_k<<<dim3(128, 4), b512, 0, stream>>>(qkb, vtb, concatb);
  // 3. r1 = x + concat @ W -> ws1b bf16 (+stats fused; residual = xb bf16)
  mgemm64_k<0, 0, 2, 1, 0><<<dim3(8, 64), b512, 0, stream>>>(
      concatb, wt, nullptr, nullptr, xb, ws1b, psum, psumsq,
      nullptr, nullptr);
  reduce_stats_k<<<dim3(32), b256, 0, stream>>>(psum, psumsq, g1, be1, scale1, shift1);
  // 4. out1b = BN1(r1) bf16
  norm_k<2><<<dim3(2048), b256, 0, stream>>>(ws1b, scale1, shift1, nullptr, out1b);
  // 5. h = relu(out1 @ W1 + b1) -> bf16
  mgemm64_k<1, 1, 1, 0, 0><<<dim3(8, 64), b512, 0, stream>>>(
      out1b, w1t, b1, hb, nullptr, nullptr, nullptr, nullptr,
      nullptr, nullptr);
  // 6. r2 = BN1(r1) + (h @ W2 + b2) -> ws2b bf16 (+stats fused)
  mgemm64_k<1, 0, 2, 1, 1><<<dim3(8, 64), b512, 0, stream>>>(
      hb, w2t, b2, nullptr, ws1b, ws2b, psum, psumsq,
      scale1, shift1);
  reduce_stats_k<<<dim3(32), b256, 0, stream>>>(psum, psumsq, g2, be2, scale2, shift2);
  // 7. final BN -> d_out (fp32)
  norm_k<0><<<dim3(2048), b256, 0, stream>>>(ws2b, scale2, shift2, out, nullptr);
}